// Round 17
// baseline (116.182 us; speedup 1.0000x reference)
//
#include <hip/hip_runtime.h>
#include <hip/hip_bf16.h>

#define LJ 256008       // T*BANDS
#define TN 32001
#define OUT_LEN 32000

typedef __attribute__((ext_vector_type(8))) short short8v;
typedef __attribute__((ext_vector_type(8))) __bf16 bf16x8;
typedef __attribute__((ext_vector_type(4))) float f32x4;

__device__ __forceinline__ unsigned short f2bu(float f) {
    union { __hip_bfloat16 h; unsigned short u; } cv; cv.h = __float2bfloat16(f); return cv.u;
}

// ---------------- h1 = relu(x @ lstm_W1 + b1), stored [i][b] (f32) ----------------
__global__ __launch_bounds__(256) void k_h1(const float* __restrict__ x,
                                            const float* __restrict__ W1,
                                            const float* __restrict__ b1,
                                            float* __restrict__ h1)
{
    int idx = blockIdx.x * 256 + threadIdx.x;   // 4096 outputs
    if (idx >= 4096) return;
    int b = idx >> 6, i = idx & 63;
    float acc = b1[i];
    #pragma unroll
    for (int f = 0; f < 16; ++f)
        acc += x[b * 16 + f] * W1[f * 64 + i];
    h1[i * 64 + b] = fmaxf(acc, 0.f);
}

// ---- big GEMM: W2 double-buffered through LDS (reg-staged, T14 split); 8 waves x 8 batches -----
// chunk = 8 rows of W2 (8 KB). wave wv stages row (chunk*8 + wv); all waves consume from LDS.
__global__ __launch_bounds__(512) void k_gemm(const float* __restrict__ W2,
                                              const float* __restrict__ b2,
                                              const float* __restrict__ h1,
                                              float* __restrict__ edc,
                                              float* __restrict__ edc1d,
                                              float* __restrict__ P)
{
    __shared__ float h1s[4096];          // 16 KB
    __shared__ float w2s[2][2048];       // 2 x 8 KB double buffer
    int tid = threadIdx.x;
    #pragma unroll
    for (int r = 0; r < 8; ++r) h1s[tid + 512 * r] = h1[tid + 512 * r];
    int lane = tid & 63, wv = tid >> 6;            // 8 waves
    int bstart = wv * 8;                           // this wave's 8 batches
    long jb4 = (long)blockIdx.x * 256 + 4 * lane;  // this lane's float4 of columns
    bool ok = jb4 < LJ;
    const float* wb = W2 + (ok ? jb4 : 0);         // clamped base: loads unconditional
    int myslot = wv * 256 + 4 * lane;              // this thread's staging slot
    float acc[8][4];
    #pragma unroll
    for (int b = 0; b < 8; ++b)
        #pragma unroll
        for (int c = 0; c < 4; ++c) acc[b][c] = 0.f;

    // prologue: stage chunk 0 (row wv)
    {
        float4 v0 = *(const float4*)(wb + (long)wv * LJ);
        *(float4*)(&w2s[0][myslot]) = v0;
    }
    __syncthreads();                               // h1s + chunk0 ready

    #pragma unroll 1
    for (int cc = 0; cc < 8; ++cc) {
        int buf = cc & 1;
        float4 vx;
        bool more = (cc + 1) < 8;
        if (more) vx = *(const float4*)(wb + (long)((cc + 1) * 8 + wv) * LJ);  // issue early
        #pragma unroll
        for (int i = 0; i < 8; ++i) {              // compute chunk cc from LDS
            float4 w = *(const float4*)(&w2s[buf][i * 256 + 4 * lane]);
            const float4* hv = (const float4*)(h1s + (cc * 8 + i) * 64 + bstart);
            float4 ha = hv[0], hb = hv[1];
            acc[0][0] += ha.x * w.x; acc[0][1] += ha.x * w.y;
            acc[0][2] += ha.x * w.z; acc[0][3] += ha.x * w.w;
            acc[1][0] += ha.y * w.x; acc[1][1] += ha.y * w.y;
            acc[1][2] += ha.y * w.z; acc[1][3] += ha.y * w.w;
            acc[2][0] += ha.z * w.x; acc[2][1] += ha.z * w.y;
            acc[2][2] += ha.z * w.z; acc[2][3] += ha.z * w.w;
            acc[3][0] += ha.w * w.x; acc[3][1] += ha.w * w.y;
            acc[3][2] += ha.w * w.z; acc[3][3] += ha.w * w.w;
            acc[4][0] += hb.x * w.x; acc[4][1] += hb.x * w.y;
            acc[4][2] += hb.x * w.z; acc[4][3] += hb.x * w.w;
            acc[5][0] += hb.y * w.x; acc[5][1] += hb.y * w.y;
            acc[5][2] += hb.y * w.z; acc[5][3] += hb.y * w.w;
            acc[6][0] += hb.z * w.x; acc[6][1] += hb.z * w.y;
            acc[6][2] += hb.z * w.z; acc[6][3] += hb.z * w.w;
            acc[7][0] += hb.w * w.x; acc[7][1] += hb.w * w.y;
            acc[7][2] += hb.w * w.z; acc[7][3] += hb.w * w.w;
        }
        if (more) *(float4*)(&w2s[buf ^ 1][myslot]) = vx;   // write late (buf^1 free since cc-1)
        __syncthreads();                                    // publish buf^1; all done reading buf
    }

    float4 z4 = make_float4(0.f, 0.f, 0.f, 0.f);
    float4 bias = ok ? *(const float4*)(b2 + jb4) : z4;
    int tcol = (int)(jb4 >> 3);                    // same t for the whole float4
    #pragma unroll
    for (int b = 0; b < 8; ++b) {
        int bb = bstart + b;
        float r0, r1, r2, r3;
        if (ok) {
            float4 v = make_float4(acc[b][0] + bias.x, acc[b][1] + bias.y,
                                   acc[b][2] + bias.z, acc[b][3] + bias.w);
            *(float4*)(edc + (long)bb * LJ + jb4) = v;
            float s = v.x + v.y + v.z + v.w;       // half of the 8-col band group
            s += __shfl_xor(s, 1);                 // partner lane has the other half
            if ((lane & 1) == 0)
                edc1d[(long)bb * TN + tcol] = s * 0.125f;
            r0 = v.x; r1 = v.y; r2 = v.z; r3 = v.w;
        } else { r0 = r1 = r2 = r3 = 0.f; }
        // reduce over same-parity lanes (band = 4*(lane&1)+e)
        r0 += __shfl_xor(r0, 2);  r1 += __shfl_xor(r1, 2);
        r2 += __shfl_xor(r2, 2);  r3 += __shfl_xor(r3, 2);
        r0 += __shfl_xor(r0, 4);  r1 += __shfl_xor(r1, 4);
        r2 += __shfl_xor(r2, 4);  r3 += __shfl_xor(r3, 4);
        r0 += __shfl_xor(r0, 8);  r1 += __shfl_xor(r1, 8);
        r2 += __shfl_xor(r2, 8);  r3 += __shfl_xor(r3, 8);
        r0 += __shfl_xor(r0, 16); r1 += __shfl_xor(r1, 16);
        r2 += __shfl_xor(r2, 16); r3 += __shfl_xor(r3, 16);
        r0 += __shfl_xor(r0, 32); r1 += __shfl_xor(r1, 32);
        r2 += __shfl_xor(r2, 32); r3 += __shfl_xor(r3, 32);
        if (lane < 2)
            *(float4*)(P + (long)blockIdx.x * 512 + bb * 8 + lane * 4)
                = make_float4(r0, r1, r2, r3);
    }
}

// ---------------- sum block partials -> sums[b][band][{all,q1,q4}] ----------------
__global__ __launch_bounds__(512) void k_redsum(const float* __restrict__ P,
                                                float* __restrict__ sums)
{
    int g = blockIdx.x, t = threadIdx.x;           // t = batch*8 + band
    int b = t >> 3, band = t & 7;
    int s0 = g * 16, s1 = s0 + 16;
    if (s1 > 1001) s1 = 1001;
    float all = 0.f, q1 = 0.f, q4 = 0.f;
    for (int blk = s0; blk < s1; ++blk) {
        float v = P[(long)blk * 512 + t];
        all += v;
        if (blk < 250) q1 += v;                    // t < 8000  <=> j < 64000
        if (blk >= 750) q4 += v;                   // t >= 24000 <=> j >= 192000
    }
    atomicAdd(&sums[b * 24 + band * 3 + 0], all);
    atomicAdd(&sums[b * 24 + band * 3 + 1], q1);
    atomicAdd(&sums[b * 24 + band * 3 + 2], q4);
}

// ---------------- small MLP head: one block per batch row, f32 outputs ----------------
__global__ __launch_bounds__(64) void k_mlp(const float* __restrict__ x,
    const float* __restrict__ sums,
    const float* __restrict__ eW1, const float* __restrict__ eb1,
    const float* __restrict__ eW2, const float* __restrict__ eb2,
    const float* __restrict__ dW1, const float* __restrict__ db1,
    const float* __restrict__ dW2, const float* __restrict__ db2,
    const float* __restrict__ aW1, const float* __restrict__ ab1,
    const float* __restrict__ aW2, const float* __restrict__ ab2,
    const float* __restrict__ bW1, const float* __restrict__ bb1,
    const float* __restrict__ bW2, const float* __restrict__ bb2,
    float* __restrict__ out_lk, float* __restrict__ out_a, float* __restrict__ out_b)
{
    int b = blockIdx.x, o = threadIdx.x;
    __shared__ float feat[16], a1[64], hh[64], t1[64];
    if (o < 16) {
        float v;
        if (o < 8) v = sums[b * 24 + o * 3] * (1.f / 32001.f);
        else {
            int band = o - 8;
            v = sums[b * 24 + band * 3 + 2] * (1.f / 8001.f)
              - sums[b * 24 + band * 3 + 1] * (1.f / 8000.f);
        }
        feat[o] = v;
    }
    __syncthreads();
    {   float acc = eb1[o];
        #pragma unroll
        for (int c = 0; c < 16; ++c) acc += feat[c] * eW1[c * 64 + o];
        a1[o] = fmaxf(acc, 0.f); }
    __syncthreads();
    {   float acc = eb2[o];
        for (int c = 0; c < 64; ++c) acc += a1[c] * eW2[c * 64 + o];
        hh[o] = fmaxf(acc, 0.f); }
    __syncthreads();
    {   float acc = db1[o];
        #pragma unroll
        for (int c = 0; c < 3; ++c) acc += x[b * 16 + c] * dW1[c * 64 + o];
        for (int c = 0; c < 64; ++c) acc += hh[c] * dW1[(3 + c) * 64 + o];
        t1[o] = fmaxf(acc, 0.f); }
    __syncthreads();
    if (o < 16) {
        float acc = db2[o];
        for (int c = 0; c < 64; ++c) acc += t1[c] * dW2[c * 16 + o];
        out_lk[b * 16 + o] = acc;
    }
    __syncthreads();
    if (o < 32) {
        float acc = ab1[o];
        for (int c = 0; c < 64; ++c) acc += hh[c] * aW1[c * 32 + o];
        t1[o] = fmaxf(acc, 0.f);
    }
    __syncthreads();
    if (o < 16) {
        float acc = ab2[o];
        for (int c = 0; c < 32; ++c) acc += t1[c] * aW2[c * 16 + o];
        out_a[b * 16 + o] = acc;
    }
    __syncthreads();
    if (o < 32) {
        float acc = bb1[o];
        for (int c = 0; c < 64; ++c) acc += hh[c] * bW1[c * 32 + o];
        t1[o] = fmaxf(acc, 0.f);
    }
    __syncthreads();
    if (o < 16) {
        float acc = bb2[o];
        for (int c = 0; c < 32; ++c) acc += t1[c] * bW2[c * 16 + o];
        out_b[b * 16 + o] = acc;
    }
}

// ---------------- parity stage 1: packed bits (per-(b, 256-chunk) inclusive XOR scan) ----------
__global__ __launch_bounds__(256) void k_par1(const int* __restrict__ flips,
                                              unsigned* __restrict__ parbits,
                                              unsigned* __restrict__ ctot)
{
    int b = blockIdx.x, c = blockIdx.y, tid = threadIdx.x;
    int t = c * 256 + tid;
    int bit = (t == 0) ? 0 : (flips[(long)b * OUT_LEN + t] & 1);
    int lane = tid & 63, wv = tid >> 6;
    unsigned long long mask = __ballot(bit != 0);
    int below = ((int)__popcll(mask & ((1ull << lane) - 1ull))) & 1;
    int incl = below ^ bit;
    __shared__ int wtot[4];
    if (lane == 0) wtot[wv] = ((int)__popcll(mask)) & 1;
    __syncthreads();
    int pre = 0;
    for (int w = 0; w < wv; ++w) pre ^= wtot[w];
    int inclB = pre ^ incl;
    unsigned long long m2 = __ballot(inclB != 0);
    if (lane == 0)  parbits[b * 1000 + c * 8 + wv * 2 + 0] = (unsigned)(m2 & 0xffffffffull);
    if (lane == 32) parbits[b * 1000 + c * 8 + wv * 2 + 1] = (unsigned)(m2 >> 32);
    if (tid == 0) ctot[c * 64 + b] = (unsigned)(wtot[0] ^ wtot[1] ^ wtot[2] ^ wtot[3]);
}

// ---------------- parity stage 2: exclusive prefix over chunks ----------------
__global__ __launch_bounds__(64) void k_par2(const unsigned* __restrict__ ctot,
                                             unsigned* __restrict__ cpref)
{
    int b = threadIdx.x;
    unsigned carry = 0;
    for (int c = 0; c < 125; ++c) {
        cpref[c * 64 + b] = carry;
        carry ^= ctot[c * 64 + b];
    }
}

// ------- MFMA Toeplitz conv (late+early) + amp + sign -> rir ----------------------------------
__global__ __launch_bounds__(512) void k_convm(const float* __restrict__ edc1d,
    const float* __restrict__ lk, const float* __restrict__ eg,
    const unsigned* __restrict__ parbits, const unsigned* __restrict__ cpref,
    float* __restrict__ rir)
{
    __shared__ float kerf[1024];
    __shared__ __align__(16) unsigned short afr[33 * 64 * 8];  // A frags [kb][lane][e]
    __shared__ __align__(16) unsigned short sbf[3136];         // swizzled bf16 window
    __shared__ float sf32[2049];
    int b = blockIdx.x, tb0 = blockIdx.y * 2048, tid = threadIdx.x;
    const float* src = edc1d + (long)b * TN;
    for (int k = tid; k < 1024; k += 512)
        kerf[k] = lk[k] + (k < 43 ? eg[k] : 0.f);
    for (int ch = tid; ch < 388; ch += 512) {
        unsigned short h[8];
        #pragma unroll
        for (int e = 0; e < 8; ++e) {
            int gt = tb0 + ch * 8 + e - 1031;
            float v = (gt >= 0 && gt <= OUT_LEN) ? src[gt] : 0.f;
            h[e] = f2bu(v);
        }
        int cs = ch ^ ((ch >> 3) & 7);
        *(uint4*)(&sbf[cs * 8]) = make_uint4(
            (unsigned)h[0] | ((unsigned)h[1] << 16), (unsigned)h[2] | ((unsigned)h[3] << 16),
            (unsigned)h[4] | ((unsigned)h[5] << 16), (unsigned)h[6] | ((unsigned)h[7] << 16));
    }
    for (int u = tid; u < 2049; u += 512) {
        int gt = tb0 + u;
        sf32[u] = (gt <= OUT_LEN) ? src[gt] : 0.f;
    }
    __syncthreads();
    for (int sl = tid; sl < 33 * 64; sl += 512) {
        int kb = sl >> 6, l = sl & 63;
        int x0 = kb * 32 - 1 + (l & 15) - 8 * (l >> 4);    // x = x0 - e
        unsigned short h[8];
        #pragma unroll
        for (int e = 0; e < 8; ++e) {
            int x = x0 - e;
            float v = (x >= 0 && x < 1024) ? kerf[x] : 0.f;
            h[e] = f2bu(v);
        }
        *(uint4*)(&afr[sl * 8]) = make_uint4(
            (unsigned)h[0] | ((unsigned)h[1] << 16), (unsigned)h[2] | ((unsigned)h[3] << 16),
            (unsigned)h[4] | ((unsigned)h[5] << 16), (unsigned)h[6] | ((unsigned)h[7] << 16));
    }
    __syncthreads();
    int lane = tid & 63, wv = tid >> 6;                    // 8 waves, 1 C-tile each
    int tb = tb0 + wv * 256;
    int cq = wv * 256 + 16 * (lane & 15) + 8 * (lane >> 4) + 1032;  // B chunk base (kb=0)
    f32x4 acc = {0.f, 0.f, 0.f, 0.f};
    for (int kb = 0; kb < 33; ++kb) {
        short8v araw = *(const short8v*)(&afr[(kb * 64 + lane) * 8]);
        int ch = (cq - (kb << 5)) >> 3;
        int cs = ch ^ ((ch >> 3) & 7);
        short8v braw = *(const short8v*)(&sbf[cs * 8]);
        union { short8v s; bf16x8 v; } ua, ub2;
        ua.s = araw; ub2.s = braw;
        acc = __builtin_amdgcn_mfma_f32_16x16x32_bf16(ua.v, ub2.v, acc, 0, 0, 0);
    }
    int c = lane & 15, q = lane >> 4;
    int t4 = tb + 16 * c + 4 * q;
    if (t4 < OUT_LEN) {
        int u0 = t4 - tb0;
        unsigned pw = parbits[b * 1000 + (t4 >> 5)];       // 4 bits same word (t4%4==0)
        unsigned cp = cpref[(t4 >> 8) * 64 + b] & 1u;
        int sh = t4 & 31;
        float sv[5];
        #pragma unroll
        for (int e = 0; e < 5; ++e) sv[e] = sf32[u0 + e];
        float r[4];
        #pragma unroll
        for (int reg = 0; reg < 4; ++reg) {
            float diff = sv[reg] - sv[reg + 1];
            float amp = diff > 0.f ? sqrtf(diff) : 0.f;
            unsigned p = ((pw >> (sh + reg)) & 1u) ^ cp;
            r[reg] = acc[reg] * amp * (p ? -1.f : 1.f);
        }
        *(float4*)(rir + (long)b * OUT_LEN + t4) = make_float4(r[0], r[1], r[2], r[3]);
    }
}

extern "C" void kernel_launch(void* const* d_in, const int* in_sizes, int n_in,
                              void* d_out, int out_size, void* d_ws, size_t ws_size,
                              hipStream_t stream) {
    (void)in_sizes; (void)n_in; (void)out_size; (void)ws_size;
    const float* x    = (const float*)d_in[0];
    const float* lW1  = (const float*)d_in[1];  const float* lb1 = (const float*)d_in[2];
    const float* lW2  = (const float*)d_in[3];  const float* lb2 = (const float*)d_in[4];
    const float* eW1  = (const float*)d_in[5];  const float* eb1 = (const float*)d_in[6];
    const float* eW2  = (const float*)d_in[7];  const float* eb2 = (const float*)d_in[8];
    const float* dW1  = (const float*)d_in[9];  const float* db1 = (const float*)d_in[10];
    const float* dW2  = (const float*)d_in[11]; const float* db2 = (const float*)d_in[12];
    const float* aW1  = (const float*)d_in[13]; const float* ab1 = (const float*)d_in[14];
    const float* aW2  = (const float*)d_in[15]; const float* ab2 = (const float*)d_in[16];
    const float* bW1  = (const float*)d_in[17]; const float* bb1 = (const float*)d_in[18];
    const float* bW2  = (const float*)d_in[19]; const float* bb2 = (const float*)d_in[20];
    const float* eg   = (const float*)d_in[21]; const float* lkk = (const float*)d_in[22];
    const int* flips  = (const int*)d_in[23];

    float* out = (float*)d_out;                    // f32 output buffer
    float* rir = out;                              // 2,048,000
    float* edc = out + 2048000;                    // 16,384,512
    float* olk = out + 18432512;                   // 1,024
    float* oa  = out + 18433536;                   // 1,024
    float* ob  = out + 18434560;                   // 1,024

    // -------- ws layout --------
    char* wsb = (char*)d_ws;
    float*    ws_h1   = (float*)(wsb + 1024);       // 16,384 B
    unsigned* ws_ct   = (unsigned*)(wsb + 18432);   // 32,000 B
    unsigned* ws_cp   = (unsigned*)(wsb + 50688);   // 32,000 B
    unsigned* ws_pb   = (unsigned*)(wsb + 82944);   // 256,000 B
    float*    ws_sums = (float*)(wsb + 339200);     // 6,144 B
    float*    ws_e1d  = (float*)(wsb + 346112);     // 8,192,256 B -> ends 8,538,368
    float*    ws_part = (float*)(wsb + 8538368);    // 1001*512*4 = 2,050,048 B

    hipMemsetAsync(ws_sums, 0, 64 * 24 * sizeof(float), stream);

    k_h1<<<16, 256, 0, stream>>>(x, lW1, lb1, ws_h1);
    k_par1<<<dim3(64, 125), 256, 0, stream>>>(flips, ws_pb, ws_ct);
    k_par2<<<1, 64, 0, stream>>>(ws_ct, ws_cp);
    k_gemm<<<1001, 512, 0, stream>>>(lW2, lb2, ws_h1, edc, ws_e1d, ws_part);
    k_redsum<<<63, 512, 0, stream>>>(ws_part, ws_sums);
    k_mlp<<<64, 64, 0, stream>>>(x, ws_sums, eW1, eb1, eW2, eb2, dW1, db1, dW2, db2,
                                 aW1, ab1, aW2, ab2, bW1, bb1, bW2, bb2, olk, oa, ob);
    k_convm<<<dim3(64, 16), 512, 0, stream>>>(ws_e1d, lkk, eg, ws_pb, ws_cp, rir);
}

// Round 18
// 115.965 us; speedup vs baseline: 1.0019x; 1.0019x over previous
//
#include <hip/hip_runtime.h>
#include <hip/hip_bf16.h>

#define LJ 256008       // T*BANDS
#define TN 32001
#define OUT_LEN 32000

typedef __attribute__((ext_vector_type(8))) short short8v;
typedef __attribute__((ext_vector_type(8))) __bf16 bf16x8;
typedef __attribute__((ext_vector_type(4))) float f32x4;

__device__ __forceinline__ unsigned short f2bu(float f) {
    union { __hip_bfloat16 h; unsigned short u; } cv; cv.h = __float2bfloat16(f); return cv.u;
}
__device__ __forceinline__ uint4 pack8(const unsigned short* h) {
    return make_uint4((unsigned)h[0] | ((unsigned)h[1] << 16),
                      (unsigned)h[2] | ((unsigned)h[3] << 16),
                      (unsigned)h[4] | ((unsigned)h[5] << 16),
                      (unsigned)h[6] | ((unsigned)h[7] << 16));
}
__device__ __forceinline__ f32x4 mfma16(uint4 a, uint4 b, f32x4 c) {
    union { uint4 u; short8v s; bf16x8 v; } ua, ub;
    ua.u = a; ub.u = b;
    return __builtin_amdgcn_mfma_f32_16x16x32_bf16(ua.v, ub.v, c, 0, 0, 0);
}

// ---------------- h1 = relu(x @ lstm_W1 + b1), stored [i][b] (f32) ----------------
__global__ __launch_bounds__(256) void k_h1(const float* __restrict__ x,
                                            const float* __restrict__ W1,
                                            const float* __restrict__ b1,
                                            float* __restrict__ h1)
{
    int idx = blockIdx.x * 256 + threadIdx.x;   // 4096 outputs
    if (idx >= 4096) return;
    int b = idx >> 6, i = idx & 63;
    float acc = b1[i];
    #pragma unroll
    for (int f = 0; f < 16; ++f)
        acc += x[b * 16 + f] * W1[f * 64 + i];
    h1[i * 64 + b] = fmaxf(acc, 0.f);
}

// ---- MFMA GEMM: edc = h1 @ W2 + b2 (bf16 MFMA, f32 acc) + exact-f32 edc1d + P partials --------
// A = h1 [batch][i]; B = W2 [i][col]. Fragment conventions identical to k_convm (HW-verified):
// A/B operand: lane holds outer = lane&15, k = 8*(lane>>4)+e.  C/D: col=lane&15, row=4*(lane>>4)+reg.
__global__ __launch_bounds__(512) void k_gemm(const float* __restrict__ W2,
                                              const float* __restrict__ b2,
                                              const float* __restrict__ h1,
                                              float* __restrict__ edc,
                                              float* __restrict__ edc1d,
                                              float* __restrict__ P)
{
    __shared__ float h1f[4096];                            // 16 KB, [i][b]
    __shared__ __align__(16) unsigned short afr[4096];     // 8 KB: [bt(4)][kb(2)][lane][e]
    __shared__ __align__(16) unsigned short bfr[8192];     // 16 KB: [ct(16)][lane][e] (per kb)
    __shared__ float wband[2048];                          // 8 KB: [i(64)][tl(32)] band-sums
    __shared__ float bband[32];                            // b2 band-sums
    int tid = threadIdx.x;
    long C0 = (long)blockIdx.x * 256;

    // stage h1 f32
    #pragma unroll
    for (int s = 0; s < 8; ++s) h1f[tid + 512 * s] = h1[tid + 512 * s];
    // stage A fragments (one slot per thread): bt=tid>>7, kb=(tid>>6)&1, l=tid&63
    {
        int bt = tid >> 7, kb = (tid >> 6) & 1, l = tid & 63;
        int q = l >> 4, r = l & 15;
        unsigned short hh[8];
        #pragma unroll
        for (int e = 0; e < 8; ++e)
            hh[e] = f2bu(h1[(32 * kb + 8 * q + e) * 64 + 16 * bt + r]);
        *(uint4*)(&afr[tid * 8]) = pack8(hh);
    }
    // stage W2 band-sums (f32-exact), 4 entries/thread: i = en>>5, tl = en&31
    #pragma unroll
    for (int s = 0; s < 4; ++s) {
        int en = tid + 512 * s;
        int i = en >> 5, tl = en & 31;
        long c8 = C0 + 8 * tl;
        float sum = 0.f;
        if (c8 + 7 < LJ) {
            float4 u0 = *(const float4*)(W2 + (long)i * LJ + c8);
            float4 u1 = *(const float4*)(W2 + (long)i * LJ + c8 + 4);
            sum = ((u0.x + u0.y) + (u0.z + u0.w)) + ((u1.x + u1.y) + (u1.z + u1.w));
        }
        wband[i * 32 + tl] = sum;
    }
    if (tid < 32) {
        long c8 = C0 + 8 * tid;
        float sum = 0.f;
        if (c8 + 7 < LJ) {
            float4 u0 = *(const float4*)(b2 + c8);
            float4 u1 = *(const float4*)(b2 + c8 + 4);
            sum = ((u0.x + u0.y) + (u0.z + u0.w)) + ((u1.x + u1.y) + (u1.z + u1.w));
        }
        bband[tid] = sum;
    }
    // stage B fragments for kb=0: 2 slots/thread: ct=sl>>6, l=sl&63
    #pragma unroll
    for (int s = 0; s < 2; ++s) {
        int sl = tid + 512 * s;
        int ct = sl >> 6, l = sl & 63;
        int q = l >> 4, r = l & 15;
        long col = C0 + 16 * ct + r;
        unsigned short hh[8];
        #pragma unroll
        for (int e = 0; e < 8; ++e) {
            float v = (col < LJ) ? W2[(long)(8 * q + e) * LJ + col] : 0.f;
            hh[e] = f2bu(v);
        }
        *(uint4*)(&bfr[sl * 8]) = pack8(hh);
    }
    __syncthreads();

    int lane = tid & 63, wv = tid >> 6;
    int q = lane >> 4, r = lane & 15;
    f32x4 acc[2][4];
    #pragma unroll
    for (int c = 0; c < 2; ++c)
        #pragma unroll
        for (int b = 0; b < 4; ++b) acc[c][b] = (f32x4){0.f, 0.f, 0.f, 0.f};

    // kb = 0
    #pragma unroll
    for (int ctl = 0; ctl < 2; ++ctl) {
        int ct = wv * 2 + ctl;
        uint4 braw = *(const uint4*)(&bfr[(ct * 64 + lane) * 8]);
        #pragma unroll
        for (int bt = 0; bt < 4; ++bt) {
            uint4 araw = *(const uint4*)(&afr[((bt * 2 + 0) * 64 + lane) * 8]);
            acc[ctl][bt] = mfma16(araw, braw, acc[ctl][bt]);
        }
    }
    __syncthreads();                                    // done reading bfr(kb=0)
    // stage B fragments for kb=1
    #pragma unroll
    for (int s = 0; s < 2; ++s) {
        int sl = tid + 512 * s;
        int ct = sl >> 6, l = sl & 63;
        int qq = l >> 4, rr = l & 15;
        long col = C0 + 16 * ct + rr;
        unsigned short hh[8];
        #pragma unroll
        for (int e = 0; e < 8; ++e) {
            float v = (col < LJ) ? W2[(long)(32 + 8 * qq + e) * LJ + col] : 0.f;
            hh[e] = f2bu(v);
        }
        *(uint4*)(&bfr[sl * 8]) = pack8(hh);
    }
    __syncthreads();
    // kb = 1
    #pragma unroll
    for (int ctl = 0; ctl < 2; ++ctl) {
        int ct = wv * 2 + ctl;
        uint4 braw = *(const uint4*)(&bfr[(ct * 64 + lane) * 8]);
        #pragma unroll
        for (int bt = 0; bt < 4; ++bt) {
            uint4 araw = *(const uint4*)(&afr[((bt * 2 + 1) * 64 + lane) * 8]);
            acc[ctl][bt] = mfma16(araw, braw, acc[ctl][bt]);
        }
    }

    // exact-f32 edc1d: 4 entries/thread: b = en>>5, tl = en&31
    #pragma unroll
    for (int s = 0; s < 4; ++s) {
        int en = tid + 512 * s;
        int b = en >> 5, tl = en & 31;
        long c8 = C0 + 8 * tl;
        if (c8 + 7 < LJ) {
            float dot = bband[tl];
            #pragma unroll 8
            for (int i = 0; i < 64; ++i)
                dot += h1f[i * 64 + b] * wband[i * 32 + tl];
            edc1d[(long)b * TN + (C0 >> 3) + tl] = dot * 0.125f;
        }
    }

    // epilogue: edc stores + band partial sums
    float psum[4][4];
    #pragma unroll
    for (int bt = 0; bt < 4; ++bt)
        #pragma unroll
        for (int rg = 0; rg < 4; ++rg) psum[bt][rg] = 0.f;
    #pragma unroll
    for (int ctl = 0; ctl < 2; ++ctl) {
        int ct = wv * 2 + ctl;
        long col = C0 + 16 * ct + r;
        bool okc = col < LJ;
        float bias = okc ? b2[col] : 0.f;
        #pragma unroll
        for (int bt = 0; bt < 4; ++bt) {
            #pragma unroll
            for (int rg = 0; rg < 4; ++rg) {
                float v = acc[ctl][bt][rg] + bias;      // 0 for invalid cols (B staged 0)
                if (okc) edc[(long)(16 * bt + 4 * q + rg) * LJ + col] = v;
                float sps = v + __shfl_xor(v, 8);       // band-sum over {r, r^8}
                psum[bt][rg] += sps;
            }
        }
    }
    if (r < 8) {
        #pragma unroll
        for (int bt = 0; bt < 4; ++bt)
            #pragma unroll
            for (int rg = 0; rg < 4; ++rg)
                P[(long)blockIdx.x * 512 + (16 * bt + 4 * q + rg) * 8 + r] = psum[bt][rg];
    }
}

// ---------------- sum block partials -> sums[b][band][{all,q1,q4}] ----------------
__global__ __launch_bounds__(512) void k_redsum(const float* __restrict__ P,
                                                float* __restrict__ sums)
{
    int g = blockIdx.x, t = threadIdx.x;           // t = batch*8 + band
    int b = t >> 3, band = t & 7;
    int s0 = g * 16, s1 = s0 + 16;
    if (s1 > 1001) s1 = 1001;
    float all = 0.f, q1 = 0.f, q4 = 0.f;
    for (int blk = s0; blk < s1; ++blk) {
        float v = P[(long)blk * 512 + t];
        all += v;
        if (blk < 250) q1 += v;                    // t < 8000  <=> j < 64000
        if (blk >= 750) q4 += v;                   // t >= 24000 <=> j >= 192000
    }
    atomicAdd(&sums[b * 24 + band * 3 + 0], all);
    atomicAdd(&sums[b * 24 + band * 3 + 1], q1);
    atomicAdd(&sums[b * 24 + band * 3 + 2], q4);
}

// ---------------- small MLP head: one block per batch row, f32 outputs ----------------
__global__ __launch_bounds__(64) void k_mlp(const float* __restrict__ x,
    const float* __restrict__ sums,
    const float* __restrict__ eW1, const float* __restrict__ eb1,
    const float* __restrict__ eW2, const float* __restrict__ eb2,
    const float* __restrict__ dW1, const float* __restrict__ db1,
    const float* __restrict__ dW2, const float* __restrict__ db2,
    const float* __restrict__ aW1, const float* __restrict__ ab1,
    const float* __restrict__ aW2, const float* __restrict__ ab2,
    const float* __restrict__ bW1, const float* __restrict__ bb1,
    const float* __restrict__ bW2, const float* __restrict__ bb2,
    float* __restrict__ out_lk, float* __restrict__ out_a, float* __restrict__ out_b)
{
    int b = blockIdx.x, o = threadIdx.x;
    __shared__ float feat[16], a1[64], hh[64], t1[64];
    if (o < 16) {
        float v;
        if (o < 8) v = sums[b * 24 + o * 3] * (1.f / 32001.f);
        else {
            int band = o - 8;
            v = sums[b * 24 + band * 3 + 2] * (1.f / 8001.f)
              - sums[b * 24 + band * 3 + 1] * (1.f / 8000.f);
        }
        feat[o] = v;
    }
    __syncthreads();
    {   float acc = eb1[o];
        #pragma unroll
        for (int c = 0; c < 16; ++c) acc += feat[c] * eW1[c * 64 + o];
        a1[o] = fmaxf(acc, 0.f); }
    __syncthreads();
    {   float acc = eb2[o];
        for (int c = 0; c < 64; ++c) acc += a1[c] * eW2[c * 64 + o];
        hh[o] = fmaxf(acc, 0.f); }
    __syncthreads();
    {   float acc = db1[o];
        #pragma unroll
        for (int c = 0; c < 3; ++c) acc += x[b * 16 + c] * dW1[c * 64 + o];
        for (int c = 0; c < 64; ++c) acc += hh[c] * dW1[(3 + c) * 64 + o];
        t1[o] = fmaxf(acc, 0.f); }
    __syncthreads();
    if (o < 16) {
        float acc = db2[o];
        for (int c = 0; c < 64; ++c) acc += t1[c] * dW2[c * 16 + o];
        out_lk[b * 16 + o] = acc;
    }
    __syncthreads();
    if (o < 32) {
        float acc = ab1[o];
        for (int c = 0; c < 64; ++c) acc += hh[c] * aW1[c * 32 + o];
        t1[o] = fmaxf(acc, 0.f);
    }
    __syncthreads();
    if (o < 16) {
        float acc = ab2[o];
        for (int c = 0; c < 32; ++c) acc += t1[c] * aW2[c * 16 + o];
        out_a[b * 16 + o] = acc;
    }
    __syncthreads();
    if (o < 32) {
        float acc = bb1[o];
        for (int c = 0; c < 64; ++c) acc += hh[c] * bW1[c * 32 + o];
        t1[o] = fmaxf(acc, 0.f);
    }
    __syncthreads();
    if (o < 16) {
        float acc = bb2[o];
        for (int c = 0; c < 32; ++c) acc += t1[c] * bW2[c * 16 + o];
        out_b[b * 16 + o] = acc;
    }
}

// ---------------- parity stage 1: packed bits (per-(b, 256-chunk) inclusive XOR scan) ----------
__global__ __launch_bounds__(256) void k_par1(const int* __restrict__ flips,
                                              unsigned* __restrict__ parbits,
                                              unsigned* __restrict__ ctot)
{
    int b = blockIdx.x, c = blockIdx.y, tid = threadIdx.x;
    int t = c * 256 + tid;
    int bit = (t == 0) ? 0 : (flips[(long)b * OUT_LEN + t] & 1);
    int lane = tid & 63, wv = tid >> 6;
    unsigned long long mask = __ballot(bit != 0);
    int below = ((int)__popcll(mask & ((1ull << lane) - 1ull))) & 1;
    int incl = below ^ bit;
    __shared__ int wtot[4];
    if (lane == 0) wtot[wv] = ((int)__popcll(mask)) & 1;
    __syncthreads();
    int pre = 0;
    for (int w = 0; w < wv; ++w) pre ^= wtot[w];
    int inclB = pre ^ incl;
    unsigned long long m2 = __ballot(inclB != 0);
    if (lane == 0)  parbits[b * 1000 + c * 8 + wv * 2 + 0] = (unsigned)(m2 & 0xffffffffull);
    if (lane == 32) parbits[b * 1000 + c * 8 + wv * 2 + 1] = (unsigned)(m2 >> 32);
    if (tid == 0) ctot[c * 64 + b] = (unsigned)(wtot[0] ^ wtot[1] ^ wtot[2] ^ wtot[3]);
}

// ---------------- parity stage 2: exclusive prefix over chunks ----------------
__global__ __launch_bounds__(64) void k_par2(const unsigned* __restrict__ ctot,
                                             unsigned* __restrict__ cpref)
{
    int b = threadIdx.x;
    unsigned carry = 0;
    for (int c = 0; c < 125; ++c) {
        cpref[c * 64 + b] = carry;
        carry ^= ctot[c * 64 + b];
    }
}

// ------- MFMA Toeplitz conv (late+early) + amp + sign -> rir ----------------------------------
__global__ __launch_bounds__(512) void k_convm(const float* __restrict__ edc1d,
    const float* __restrict__ lk, const float* __restrict__ eg,
    const unsigned* __restrict__ parbits, const unsigned* __restrict__ cpref,
    float* __restrict__ rir)
{
    __shared__ float kerf[1024];
    __shared__ __align__(16) unsigned short afr[33 * 64 * 8];  // A frags [kb][lane][e]
    __shared__ __align__(16) unsigned short sbf[3136];         // swizzled bf16 window
    __shared__ float sf32[2049];
    int b = blockIdx.x, tb0 = blockIdx.y * 2048, tid = threadIdx.x;
    const float* src = edc1d + (long)b * TN;
    for (int k = tid; k < 1024; k += 512)
        kerf[k] = lk[k] + (k < 43 ? eg[k] : 0.f);
    for (int ch = tid; ch < 388; ch += 512) {
        unsigned short h[8];
        #pragma unroll
        for (int e = 0; e < 8; ++e) {
            int gt = tb0 + ch * 8 + e - 1031;
            float v = (gt >= 0 && gt <= OUT_LEN) ? src[gt] : 0.f;
            h[e] = f2bu(v);
        }
        int cs = ch ^ ((ch >> 3) & 7);
        *(uint4*)(&sbf[cs * 8]) = pack8(h);
    }
    for (int u = tid; u < 2049; u += 512) {
        int gt = tb0 + u;
        sf32[u] = (gt <= OUT_LEN) ? src[gt] : 0.f;
    }
    __syncthreads();
    for (int sl = tid; sl < 33 * 64; sl += 512) {
        int kb = sl >> 6, l = sl & 63;
        int x0 = kb * 32 - 1 + (l & 15) - 8 * (l >> 4);    // x = x0 - e
        unsigned short h[8];
        #pragma unroll
        for (int e = 0; e < 8; ++e) {
            int x = x0 - e;
            float v = (x >= 0 && x < 1024) ? kerf[x] : 0.f;
            h[e] = f2bu(v);
        }
        *(uint4*)(&afr[sl * 8]) = pack8(h);
    }
    __syncthreads();
    int lane = tid & 63, wv = tid >> 6;                    // 8 waves, 1 C-tile each
    int tb = tb0 + wv * 256;
    int cq = wv * 256 + 16 * (lane & 15) + 8 * (lane >> 4) + 1032;  // B chunk base (kb=0)
    f32x4 acc = {0.f, 0.f, 0.f, 0.f};
    for (int kb = 0; kb < 33; ++kb) {
        uint4 araw = *(const uint4*)(&afr[(kb * 64 + lane) * 8]);
        int ch = (cq - (kb << 5)) >> 3;
        int cs = ch ^ ((ch >> 3) & 7);
        uint4 braw = *(const uint4*)(&sbf[cs * 8]);
        acc = mfma16(araw, braw, acc);
    }
    int c = lane & 15, q = lane >> 4;
    int t4 = tb + 16 * c + 4 * q;
    if (t4 < OUT_LEN) {
        int u0 = t4 - tb0;
        unsigned pw = parbits[b * 1000 + (t4 >> 5)];       // 4 bits same word (t4%4==0)
        unsigned cp = cpref[(t4 >> 8) * 64 + b] & 1u;
        int sh = t4 & 31;
        float sv[5];
        #pragma unroll
        for (int e = 0; e < 5; ++e) sv[e] = sf32[u0 + e];
        float r[4];
        #pragma unroll
        for (int reg = 0; reg < 4; ++reg) {
            float diff = sv[reg] - sv[reg + 1];
            float amp = diff > 0.f ? sqrtf(diff) : 0.f;
            unsigned p = ((pw >> (sh + reg)) & 1u) ^ cp;
            r[reg] = acc[reg] * amp * (p ? -1.f : 1.f);
        }
        *(float4*)(rir + (long)b * OUT_LEN + t4) = make_float4(r[0], r[1], r[2], r[3]);
    }
}

extern "C" void kernel_launch(void* const* d_in, const int* in_sizes, int n_in,
                              void* d_out, int out_size, void* d_ws, size_t ws_size,
                              hipStream_t stream) {
    (void)in_sizes; (void)n_in; (void)out_size; (void)ws_size;
    const float* x    = (const float*)d_in[0];
    const float* lW1  = (const float*)d_in[1];  const float* lb1 = (const float*)d_in[2];
    const float* lW2  = (const float*)d_in[3];  const float* lb2 = (const float*)d_in[4];
    const float* eW1  = (const float*)d_in[5];  const float* eb1 = (const float*)d_in[6];
    const float* eW2  = (const float*)d_in[7];  const float* eb2 = (const float*)d_in[8];
    const float* dW1  = (const float*)d_in[9];  const float* db1 = (const float*)d_in[10];
    const float* dW2  = (const float*)d_in[11]; const float* db2 = (const float*)d_in[12];
    const float* aW1  = (const float*)d_in[13]; const float* ab1 = (const float*)d_in[14];
    const float* aW2  = (const float*)d_in[15]; const float* ab2 = (const float*)d_in[16];
    const float* bW1  = (const float*)d_in[17]; const float* bb1 = (const float*)d_in[18];
    const float* bW2  = (const float*)d_in[19]; const float* bb2 = (const float*)d_in[20];
    const float* eg   = (const float*)d_in[21]; const float* lkk = (const float*)d_in[22];
    const int* flips  = (const int*)d_in[23];

    float* out = (float*)d_out;                    // f32 output buffer
    float* rir = out;                              // 2,048,000
    float* edc = out + 2048000;                    // 16,384,512
    float* olk = out + 18432512;                   // 1,024
    float* oa  = out + 18433536;                   // 1,024
    float* ob  = out + 18434560;                   // 1,024

    // -------- ws layout --------
    char* wsb = (char*)d_ws;
    float*    ws_h1   = (float*)(wsb + 1024);       // 16,384 B
    unsigned* ws_ct   = (unsigned*)(wsb + 18432);   // 32,000 B
    unsigned* ws_cp   = (unsigned*)(wsb + 50688);   // 32,000 B
    unsigned* ws_pb   = (unsigned*)(wsb + 82944);   // 256,000 B
    float*    ws_sums = (float*)(wsb + 339200);     // 6,144 B
    float*    ws_e1d  = (float*)(wsb + 346112);     // 8,192,256 B -> ends 8,538,368
    float*    ws_part = (float*)(wsb + 8538368);    // 1001*512*4 = 2,050,048 B

    hipMemsetAsync(ws_sums, 0, 64 * 24 * sizeof(float), stream);

    k_h1<<<16, 256, 0, stream>>>(x, lW1, lb1, ws_h1);
    k_par1<<<dim3(64, 125), 256, 0, stream>>>(flips, ws_pb, ws_ct);
    k_par2<<<1, 64, 0, stream>>>(ws_ct, ws_cp);
    k_gemm<<<1001, 512, 0, stream>>>(lW2, lb2, ws_h1, edc, ws_e1d, ws_part);
    k_redsum<<<63, 512, 0, stream>>>(ws_part, ws_sums);
    k_mlp<<<64, 64, 0, stream>>>(x, ws_sums, eW1, eb1, eW2, eb2, dW1, db1, dW2, db2,
                                 aW1, ab1, aW2, ab2, bW1, bb1, bW2, bb2, olk, oa, ob);
    k_convm<<<dim3(64, 16), 512, 0, stream>>>(ws_e1d, lkk, eg, ws_pb, ws_cp, rir);
}

// Round 19
// 101.286 us; speedup vs baseline: 1.1471x; 1.1449x over previous
//
#include <hip/hip_runtime.h>
#include <hip/hip_bf16.h>

#define LJ 256008       // T*BANDS
#define TN 32001
#define OUT_LEN 32000

typedef __attribute__((ext_vector_type(8))) short short8v;
typedef __attribute__((ext_vector_type(8))) __bf16 bf16x8;
typedef __attribute__((ext_vector_type(4))) float f32x4;

__device__ __forceinline__ unsigned short f2bu(float f) {
    union { __hip_bfloat16 h; unsigned short u; } cv; cv.h = __float2bfloat16(f); return cv.u;
}
__device__ __forceinline__ uint4 pack8(const unsigned short* h) {
    return make_uint4((unsigned)h[0] | ((unsigned)h[1] << 16),
                      (unsigned)h[2] | ((unsigned)h[3] << 16),
                      (unsigned)h[4] | ((unsigned)h[5] << 16),
                      (unsigned)h[6] | ((unsigned)h[7] << 16));
}
__device__ __forceinline__ f32x4 mfma16(uint4 a, uint4 b, f32x4 c) {
    union { uint4 u; short8v s; bf16x8 v; } ua, ub;
    ua.u = a; ub.u = b;
    return __builtin_amdgcn_mfma_f32_16x16x32_bf16(ua.v, ub.v, c, 0, 0, 0);
}

// ---------------- h1 = relu(x @ lstm_W1 + b1), stored [i][b] (f32) ----------------
__global__ __launch_bounds__(256) void k_h1(const float* __restrict__ x,
                                            const float* __restrict__ W1,
                                            const float* __restrict__ b1,
                                            float* __restrict__ h1)
{
    int idx = blockIdx.x * 256 + threadIdx.x;   // 4096 outputs
    if (idx >= 4096) return;
    int b = idx >> 6, i = idx & 63;
    float acc = b1[i];
    #pragma unroll
    for (int f = 0; f < 16; ++f)
        acc += x[b * 16 + f] * W1[f * 64 + i];
    h1[i * 64 + b] = fmaxf(acc, 0.f);
}

// ---- MFMA GEMM, single W2 read: W2 chunk staged f32 in LDS (coalesced), B-frags + band-sums
//      + exact-f32 edc1d all derived from LDS.  Fragment conventions HW-verified (k_convm).
__global__ __launch_bounds__(512) void k_gemm(const float* __restrict__ W2,
                                              const float* __restrict__ b2,
                                              const float* __restrict__ h1,
                                              float* __restrict__ edc,
                                              float* __restrict__ edc1d,
                                              float* __restrict__ P)
{
    __shared__ float h1f[4096];                            // 16 KB, [i][b]
    __shared__ float w2f[8192];                            // 32 KB: [row(32)][col(256)] f32 chunk
    __shared__ __align__(16) unsigned short afr[4096];     // 8 KB: [bt(4)][kb(2)][lane][e]
    __shared__ float wband[2048];                          // 8 KB: [i(64)][tl(32)] band-sums
    __shared__ float bband[32];
    int tid = threadIdx.x;
    long C0 = (long)blockIdx.x * 256;
    float4 z4 = make_float4(0.f, 0.f, 0.f, 0.f);

    // stage h1 f32
    #pragma unroll
    for (int s = 0; s < 8; ++s) h1f[tid + 512 * s] = h1[tid + 512 * s];
    // stage A fragments (one slot per thread): bt=tid>>7, kb=(tid>>6)&1, l=tid&63
    {
        int bt = tid >> 7, kb = (tid >> 6) & 1, l = tid & 63;
        int q = l >> 4, r = l & 15;
        unsigned short hh[8];
        #pragma unroll
        for (int e = 0; e < 8; ++e)
            hh[e] = f2bu(h1[(32 * kb + 8 * q + e) * 64 + 16 * bt + r]);
        *(uint4*)(&afr[tid * 8]) = pack8(hh);
    }
    // b2 band-sums
    if (tid < 32) {
        long c8 = C0 + 8 * tid;
        float sum = 0.f;
        if (c8 + 7 < LJ) {
            float4 u0 = *(const float4*)(b2 + c8);
            float4 u1 = *(const float4*)(b2 + c8 + 4);
            sum = ((u0.x + u0.y) + (u0.z + u0.w)) + ((u1.x + u1.y) + (u1.z + u1.w));
        }
        bband[tid] = sum;
    }
    // stage w2f chunk kb=0 (rows 0..31), coalesced float4
    #pragma unroll
    for (int s = 0; s < 4; ++s) {
        int slot = tid + 512 * s;                      // 2048 float4 slots
        int row = slot >> 6, c4 = slot & 63;
        long col = C0 + 4 * c4;
        float4 v = (col < LJ) ? *(const float4*)(W2 + (long)row * LJ + col) : z4;
        *(float4*)(&w2f[row * 256 + 4 * c4]) = v;
    }
    __syncthreads();

    int lane = tid & 63, wv = tid >> 6;
    int q = lane >> 4, r = lane & 15;
    f32x4 acc[2][4];
    #pragma unroll
    for (int c = 0; c < 2; ++c)
        #pragma unroll
        for (int b = 0; b < 4; ++b) acc[c][b] = (f32x4){0.f, 0.f, 0.f, 0.f};

    // wband rows 0..31 from LDS
    #pragma unroll
    for (int s = 0; s < 2; ++s) {
        int en = tid + 512 * s;                        // 1024 entries
        int i = en >> 5, tl = en & 31;
        const float* p = &w2f[i * 256 + 8 * tl];
        wband[i * 32 + tl] = ((p[0] + p[1]) + (p[2] + p[3])) + ((p[4] + p[5]) + (p[6] + p[7]));
    }
    // MFMA kb=0, B frags from LDS
    #pragma unroll
    for (int ctl = 0; ctl < 2; ++ctl) {
        int ct = wv * 2 + ctl;
        unsigned short hh[8];
        #pragma unroll
        for (int e = 0; e < 8; ++e)
            hh[e] = f2bu(w2f[(8 * q + e) * 256 + 16 * ct + r]);
        uint4 braw = pack8(hh);
        #pragma unroll
        for (int bt = 0; bt < 4; ++bt) {
            uint4 araw = *(const uint4*)(&afr[((bt * 2 + 0) * 64 + lane) * 8]);
            acc[ctl][bt] = mfma16(araw, braw, acc[ctl][bt]);
        }
    }
    __syncthreads();                                   // done reading w2f(kb0)
    // stage w2f chunk kb=1 (rows 32..63)
    #pragma unroll
    for (int s = 0; s < 4; ++s) {
        int slot = tid + 512 * s;
        int row = slot >> 6, c4 = slot & 63;
        long col = C0 + 4 * c4;
        float4 v = (col < LJ) ? *(const float4*)(W2 + (long)(32 + row) * LJ + col) : z4;
        *(float4*)(&w2f[row * 256 + 4 * c4]) = v;
    }
    __syncthreads();
    // wband rows 32..63
    #pragma unroll
    for (int s = 0; s < 2; ++s) {
        int en = tid + 512 * s;
        int i2 = en >> 5, tl = en & 31;
        const float* p = &w2f[i2 * 256 + 8 * tl];
        wband[(32 + i2) * 32 + tl] = ((p[0] + p[1]) + (p[2] + p[3])) + ((p[4] + p[5]) + (p[6] + p[7]));
    }
    // MFMA kb=1
    #pragma unroll
    for (int ctl = 0; ctl < 2; ++ctl) {
        int ct = wv * 2 + ctl;
        unsigned short hh[8];
        #pragma unroll
        for (int e = 0; e < 8; ++e)
            hh[e] = f2bu(w2f[(8 * q + e) * 256 + 16 * ct + r]);
        uint4 braw = pack8(hh);
        #pragma unroll
        for (int bt = 0; bt < 4; ++bt) {
            uint4 araw = *(const uint4*)(&afr[((bt * 2 + 1) * 64 + lane) * 8]);
            acc[ctl][bt] = mfma16(araw, braw, acc[ctl][bt]);
        }
    }
    __syncthreads();                                   // wband complete

    // exact-f32 edc1d: 4 entries/thread: b = en>>5, tl = en&31
    #pragma unroll
    for (int s = 0; s < 4; ++s) {
        int en = tid + 512 * s;
        int b = en >> 5, tl = en & 31;
        long c8 = C0 + 8 * tl;
        if (c8 + 7 < LJ) {
            float dot = bband[tl];
            #pragma unroll 8
            for (int i = 0; i < 64; ++i)
                dot += h1f[i * 64 + b] * wband[i * 32 + tl];
            edc1d[(long)b * TN + (C0 >> 3) + tl] = dot * 0.125f;
        }
    }

    // epilogue: edc stores + band partial sums
    float psum[4][4];
    #pragma unroll
    for (int bt = 0; bt < 4; ++bt)
        #pragma unroll
        for (int rg = 0; rg < 4; ++rg) psum[bt][rg] = 0.f;
    #pragma unroll
    for (int ctl = 0; ctl < 2; ++ctl) {
        int ct = wv * 2 + ctl;
        long col = C0 + 16 * ct + r;
        bool okc = col < LJ;
        float bias = okc ? b2[col] : 0.f;
        #pragma unroll
        for (int bt = 0; bt < 4; ++bt) {
            #pragma unroll
            for (int rg = 0; rg < 4; ++rg) {
                float v = acc[ctl][bt][rg] + bias;      // 0 for invalid cols (B staged 0)
                if (okc) edc[(long)(16 * bt + 4 * q + rg) * LJ + col] = v;
                float sps = v + __shfl_xor(v, 8);       // band-sum over {r, r^8}
                psum[bt][rg] += sps;
            }
        }
    }
    if (r < 8) {
        #pragma unroll
        for (int bt = 0; bt < 4; ++bt)
            #pragma unroll
            for (int rg = 0; rg < 4; ++rg)
                P[(long)blockIdx.x * 512 + (16 * bt + 4 * q + rg) * 8 + r] = psum[bt][rg];
    }
}

// ---------------- sum block partials -> sums[b][band][{all,q1,q4}] ----------------
__global__ __launch_bounds__(512) void k_redsum(const float* __restrict__ P,
                                                float* __restrict__ sums)
{
    int g = blockIdx.x, t = threadIdx.x;           // t = batch*8 + band
    int b = t >> 3, band = t & 7;
    int s0 = g * 16, s1 = s0 + 16;
    if (s1 > 1001) s1 = 1001;
    float all = 0.f, q1 = 0.f, q4 = 0.f;
    for (int blk = s0; blk < s1; ++blk) {
        float v = P[(long)blk * 512 + t];
        all += v;
        if (blk < 250) q1 += v;                    // t < 8000  <=> j < 64000
        if (blk >= 750) q4 += v;                   // t >= 24000 <=> j >= 192000
    }
    atomicAdd(&sums[b * 24 + band * 3 + 0], all);
    atomicAdd(&sums[b * 24 + band * 3 + 1], q1);
    atomicAdd(&sums[b * 24 + band * 3 + 2], q4);
}

// ---------------- small MLP head: one block per batch row, f32 outputs ----------------
__global__ __launch_bounds__(64) void k_mlp(const float* __restrict__ x,
    const float* __restrict__ sums,
    const float* __restrict__ eW1, const float* __restrict__ eb1,
    const float* __restrict__ eW2, const float* __restrict__ eb2,
    const float* __restrict__ dW1, const float* __restrict__ db1,
    const float* __restrict__ dW2, const float* __restrict__ db2,
    const float* __restrict__ aW1, const float* __restrict__ ab1,
    const float* __restrict__ aW2, const float* __restrict__ ab2,
    const float* __restrict__ bW1, const float* __restrict__ bb1,
    const float* __restrict__ bW2, const float* __restrict__ bb2,
    float* __restrict__ out_lk, float* __restrict__ out_a, float* __restrict__ out_b)
{
    int b = blockIdx.x, o = threadIdx.x;
    __shared__ float feat[16], a1[64], hh[64], t1[64];
    if (o < 16) {
        float v;
        if (o < 8) v = sums[b * 24 + o * 3] * (1.f / 32001.f);
        else {
            int band = o - 8;
            v = sums[b * 24 + band * 3 + 2] * (1.f / 8001.f)
              - sums[b * 24 + band * 3 + 1] * (1.f / 8000.f);
        }
        feat[o] = v;
    }
    __syncthreads();
    {   float acc = eb1[o];
        #pragma unroll
        for (int c = 0; c < 16; ++c) acc += feat[c] * eW1[c * 64 + o];
        a1[o] = fmaxf(acc, 0.f); }
    __syncthreads();
    {   float acc = eb2[o];
        for (int c = 0; c < 64; ++c) acc += a1[c] * eW2[c * 64 + o];
        hh[o] = fmaxf(acc, 0.f); }
    __syncthreads();
    {   float acc = db1[o];
        #pragma unroll
        for (int c = 0; c < 3; ++c) acc += x[b * 16 + c] * dW1[c * 64 + o];
        for (int c = 0; c < 64; ++c) acc += hh[c] * dW1[(3 + c) * 64 + o];
        t1[o] = fmaxf(acc, 0.f); }
    __syncthreads();
    if (o < 16) {
        float acc = db2[o];
        for (int c = 0; c < 64; ++c) acc += t1[c] * dW2[c * 16 + o];
        out_lk[b * 16 + o] = acc;
    }
    __syncthreads();
    if (o < 32) {
        float acc = ab1[o];
        for (int c = 0; c < 64; ++c) acc += hh[c] * aW1[c * 32 + o];
        t1[o] = fmaxf(acc, 0.f);
    }
    __syncthreads();
    if (o < 16) {
        float acc = ab2[o];
        for (int c = 0; c < 32; ++c) acc += t1[c] * aW2[c * 16 + o];
        out_a[b * 16 + o] = acc;
    }
    __syncthreads();
    if (o < 32) {
        float acc = bb1[o];
        for (int c = 0; c < 64; ++c) acc += hh[c] * bW1[c * 32 + o];
        t1[o] = fmaxf(acc, 0.f);
    }
    __syncthreads();
    if (o < 16) {
        float acc = bb2[o];
        for (int c = 0; c < 32; ++c) acc += t1[c] * bW2[c * 16 + o];
        out_b[b * 16 + o] = acc;
    }
}

// ---------------- parity stage 1: packed bits (per-(b, 256-chunk) inclusive XOR scan) ----------
__global__ __launch_bounds__(256) void k_par1(const int* __restrict__ flips,
                                              unsigned* __restrict__ parbits,
                                              unsigned* __restrict__ ctot)
{
    int b = blockIdx.x, c = blockIdx.y, tid = threadIdx.x;
    int t = c * 256 + tid;
    int bit = (t == 0) ? 0 : (flips[(long)b * OUT_LEN + t] & 1);
    int lane = tid & 63, wv = tid >> 6;
    unsigned long long mask = __ballot(bit != 0);
    int below = ((int)__popcll(mask & ((1ull << lane) - 1ull))) & 1;
    int incl = below ^ bit;
    __shared__ int wtot[4];
    if (lane == 0) wtot[wv] = ((int)__popcll(mask)) & 1;
    __syncthreads();
    int pre = 0;
    for (int w = 0; w < wv; ++w) pre ^= wtot[w];
    int inclB = pre ^ incl;
    unsigned long long m2 = __ballot(inclB != 0);
    if (lane == 0)  parbits[b * 1000 + c * 8 + wv * 2 + 0] = (unsigned)(m2 & 0xffffffffull);
    if (lane == 32) parbits[b * 1000 + c * 8 + wv * 2 + 1] = (unsigned)(m2 >> 32);
    if (tid == 0) ctot[c * 64 + b] = (unsigned)(wtot[0] ^ wtot[1] ^ wtot[2] ^ wtot[3]);
}

// ---------------- parity stage 2: exclusive prefix over chunks ----------------
__global__ __launch_bounds__(64) void k_par2(const unsigned* __restrict__ ctot,
                                             unsigned* __restrict__ cpref)
{
    int b = threadIdx.x;
    unsigned carry = 0;
    for (int c = 0; c < 125; ++c) {
        cpref[c * 64 + b] = carry;
        carry ^= ctot[c * 64 + b];
    }
}

// ------- MFMA Toeplitz conv (late+early) + amp + sign -> rir ----------------------------------
__global__ __launch_bounds__(512) void k_convm(const float* __restrict__ edc1d,
    const float* __restrict__ lk, const float* __restrict__ eg,
    const unsigned* __restrict__ parbits, const unsigned* __restrict__ cpref,
    float* __restrict__ rir)
{
    __shared__ float kerf[1024];
    __shared__ __align__(16) unsigned short afr[33 * 64 * 8];  // A frags [kb][lane][e]
    __shared__ __align__(16) unsigned short sbf[3136];         // swizzled bf16 window
    __shared__ float sf32[2049];
    int b = blockIdx.x, tb0 = blockIdx.y * 2048, tid = threadIdx.x;
    const float* src = edc1d + (long)b * TN;
    for (int k = tid; k < 1024; k += 512)
        kerf[k] = lk[k] + (k < 43 ? eg[k] : 0.f);
    for (int ch = tid; ch < 388; ch += 512) {
        unsigned short h[8];
        #pragma unroll
        for (int e = 0; e < 8; ++e) {
            int gt = tb0 + ch * 8 + e - 1031;
            float v = (gt >= 0 && gt <= OUT_LEN) ? src[gt] : 0.f;
            h[e] = f2bu(v);
        }
        int cs = ch ^ ((ch >> 3) & 7);
        *(uint4*)(&sbf[cs * 8]) = pack8(h);
    }
    for (int u = tid; u < 2049; u += 512) {
        int gt = tb0 + u;
        sf32[u] = (gt <= OUT_LEN) ? src[gt] : 0.f;
    }
    __syncthreads();
    for (int sl = tid; sl < 33 * 64; sl += 512) {
        int kb = sl >> 6, l = sl & 63;
        int x0 = kb * 32 - 1 + (l & 15) - 8 * (l >> 4);    // x = x0 - e
        unsigned short h[8];
        #pragma unroll
        for (int e = 0; e < 8; ++e) {
            int x = x0 - e;
            float v = (x >= 0 && x < 1024) ? kerf[x] : 0.f;
            h[e] = f2bu(v);
        }
        *(uint4*)(&afr[sl * 8]) = pack8(h);
    }
    __syncthreads();
    int lane = tid & 63, wv = tid >> 6;                    // 8 waves, 1 C-tile each
    int tb = tb0 + wv * 256;
    int cq = wv * 256 + 16 * (lane & 15) + 8 * (lane >> 4) + 1032;  // B chunk base (kb=0)
    f32x4 acc = {0.f, 0.f, 0.f, 0.f};
    for (int kb = 0; kb < 33; ++kb) {
        uint4 araw = *(const uint4*)(&afr[(kb * 64 + lane) * 8]);
        int ch = (cq - (kb << 5)) >> 3;
        int cs = ch ^ ((ch >> 3) & 7);
        uint4 braw = *(const uint4*)(&sbf[cs * 8]);
        acc = mfma16(araw, braw, acc);
    }
    int c = lane & 15, q = lane >> 4;
    int t4 = tb + 16 * c + 4 * q;
    if (t4 < OUT_LEN) {
        int u0 = t4 - tb0;
        unsigned pw = parbits[b * 1000 + (t4 >> 5)];       // 4 bits same word (t4%4==0)
        unsigned cp = cpref[(t4 >> 8) * 64 + b] & 1u;
        int sh = t4 & 31;
        float sv[5];
        #pragma unroll
        for (int e = 0; e < 5; ++e) sv[e] = sf32[u0 + e];
        float r[4];
        #pragma unroll
        for (int reg = 0; reg < 4; ++reg) {
            float diff = sv[reg] - sv[reg + 1];
            float amp = diff > 0.f ? sqrtf(diff) : 0.f;
            unsigned p = ((pw >> (sh + reg)) & 1u) ^ cp;
            r[reg] = acc[reg] * amp * (p ? -1.f : 1.f);
        }
        *(float4*)(rir + (long)b * OUT_LEN + t4) = make_float4(r[0], r[1], r[2], r[3]);
    }
}

extern "C" void kernel_launch(void* const* d_in, const int* in_sizes, int n_in,
                              void* d_out, int out_size, void* d_ws, size_t ws_size,
                              hipStream_t stream) {
    (void)in_sizes; (void)n_in; (void)out_size; (void)ws_size;
    const float* x    = (const float*)d_in[0];
    const float* lW1  = (const float*)d_in[1];  const float* lb1 = (const float*)d_in[2];
    const float* lW2  = (const float*)d_in[3];  const float* lb2 = (const float*)d_in[4];
    const float* eW1  = (const float*)d_in[5];  const float* eb1 = (const float*)d_in[6];
    const float* eW2  = (const float*)d_in[7];  const float* eb2 = (const float*)d_in[8];
    const float* dW1  = (const float*)d_in[9];  const float* db1 = (const float*)d_in[10];
    const float* dW2  = (const float*)d_in[11]; const float* db2 = (const float*)d_in[12];
    const float* aW1  = (const float*)d_in[13]; const float* ab1 = (const float*)d_in[14];
    const float* aW2  = (const float*)d_in[15]; const float* ab2 = (const float*)d_in[16];
    const float* bW1  = (const float*)d_in[17]; const float* bb1 = (const float*)d_in[18];
    const float* bW2  = (const float*)d_in[19]; const float* bb2 = (const float*)d_in[20];
    const float* eg   = (const float*)d_in[21]; const float* lkk = (const float*)d_in[22];
    const int* flips  = (const int*)d_in[23];

    float* out = (float*)d_out;                    // f32 output buffer
    float* rir = out;                              // 2,048,000
    float* edc = out + 2048000;                    // 16,384,512
    float* olk = out + 18432512;                   // 1,024
    float* oa  = out + 18433536;                   // 1,024
    float* ob  = out + 18434560;                   // 1,024

    // -------- ws layout --------
    char* wsb = (char*)d_ws;
    float*    ws_h1   = (float*)(wsb + 1024);       // 16,384 B
    unsigned* ws_ct   = (unsigned*)(wsb + 18432);   // 32,000 B
    unsigned* ws_cp   = (unsigned*)(wsb + 50688);   // 32,000 B
    unsigned* ws_pb   = (unsigned*)(wsb + 82944);   // 256,000 B
    float*    ws_sums = (float*)(wsb + 339200);     // 6,144 B
    float*    ws_e1d  = (float*)(wsb + 346112);     // 8,192,256 B -> ends 8,538,368
    float*    ws_part = (float*)(wsb + 8538368);    // 1001*512*4 = 2,050,048 B

    hipMemsetAsync(ws_sums, 0, 64 * 24 * sizeof(float), stream);

    k_h1<<<16, 256, 0, stream>>>(x, lW1, lb1, ws_h1);
    k_par1<<<dim3(64, 125), 256, 0, stream>>>(flips, ws_pb, ws_ct);
    k_par2<<<1, 64, 0, stream>>>(ws_ct, ws_cp);
    k_gemm<<<1001, 512, 0, stream>>>(lW2, lb2, ws_h1, edc, ws_e1d, ws_part);
    k_redsum<<<63, 512, 0, stream>>>(ws_part, ws_sums);
    k_mlp<<<64, 64, 0, stream>>>(x, ws_sums, eW1, eb1, eW2, eb2, dW1, db1, dW2, db2,
                                 aW1, ab1, aW2, ab2, bW1, bb1, bW2, bb2, olk, oa, ob);
    k_convm<<<dim3(64, 16), 512, 0, stream>>>(ws_e1d, lkk, eg, ws_pb, ws_cp, rir);
}

// Round 20
// 95.186 us; speedup vs baseline: 1.2206x; 1.0641x over previous
//
#include <hip/hip_runtime.h>
#include <hip/hip_bf16.h>

#define LJ 256008       // T*BANDS
#define TN 32001
#define OUT_LEN 32000

typedef __attribute__((ext_vector_type(8))) short short8v;
typedef __attribute__((ext_vector_type(8))) __bf16 bf16x8;
typedef __attribute__((ext_vector_type(4))) float f32x4;

__device__ __forceinline__ unsigned short f2bu(float f) {
    union { __hip_bfloat16 h; unsigned short u; } cv; cv.h = __float2bfloat16(f); return cv.u;
}
__device__ __forceinline__ uint4 pack8(const unsigned short* h) {
    return make_uint4((unsigned)h[0] | ((unsigned)h[1] << 16),
                      (unsigned)h[2] | ((unsigned)h[3] << 16),
                      (unsigned)h[4] | ((unsigned)h[5] << 16),
                      (unsigned)h[6] | ((unsigned)h[7] << 16));
}
__device__ __forceinline__ f32x4 mfma16(uint4 a, uint4 b, f32x4 c) {
    union { uint4 u; short8v s; bf16x8 v; } ua, ub;
    ua.u = a; ub.u = b;
    return __builtin_amdgcn_mfma_f32_16x16x32_bf16(ua.v, ub.v, c, 0, 0, 0);
}

// ---------------- h1 = relu(x @ lstm_W1 + b1), stored [i][b] (f32) ----------------
__global__ __launch_bounds__(256) void k_h1(const float* __restrict__ x,
                                            const float* __restrict__ W1,
                                            const float* __restrict__ b1,
                                            float* __restrict__ h1)
{
    int idx = blockIdx.x * 256 + threadIdx.x;   // 4096 outputs
    if (idx >= 4096) return;
    int b = idx >> 6, i = idx & 63;
    float acc = b1[i];
    #pragma unroll
    for (int f = 0; f < 16; ++f)
        acc += x[b * 16 + f] * W1[f * 64 + i];
    h1[i * 64 + b] = fmaxf(acc, 0.f);
}

// ---- MFMA GEMM, single W2 read; edc1d dot vectorized via transposed LDS (b128 reads) ----------
__global__ __launch_bounds__(512) void k_gemm(const float* __restrict__ W2,
                                              const float* __restrict__ b2,
                                              const float* __restrict__ h1,
                                              float* __restrict__ edc,
                                              float* __restrict__ edc1d,
                                              float* __restrict__ P)
{
    __shared__ float h1T[64 * 68];                         // 17.4 KB: [b][i], pad 68
    __shared__ float w2f[8192];                            // 32 KB: [row(32)][col(256)] f32 chunk
    __shared__ __align__(16) unsigned short afr[4096];     // 8 KB: [bt(4)][kb(2)][lane][e]
    __shared__ float wbandT[32 * 68];                      // 8.7 KB: [tl][i], pad 68
    __shared__ float bband[32];
    int tid = threadIdx.x;
    long C0 = (long)blockIdx.x * 256;
    float4 z4 = make_float4(0.f, 0.f, 0.f, 0.f);

    // stage h1 transposed: [b][i]
    #pragma unroll
    for (int s = 0; s < 8; ++s) {
        int g = tid + 512 * s;
        float v = h1[g];
        h1T[(g & 63) * 68 + (g >> 6)] = v;
    }
    // stage A fragments (one slot per thread): bt=tid>>7, kb=(tid>>6)&1, l=tid&63
    {
        int bt = tid >> 7, kb = (tid >> 6) & 1, l = tid & 63;
        int q = l >> 4, r = l & 15;
        unsigned short hh[8];
        #pragma unroll
        for (int e = 0; e < 8; ++e)
            hh[e] = f2bu(h1[(32 * kb + 8 * q + e) * 64 + 16 * bt + r]);
        *(uint4*)(&afr[tid * 8]) = pack8(hh);
    }
    // b2 band-sums
    if (tid < 32) {
        long c8 = C0 + 8 * tid;
        float sum = 0.f;
        if (c8 + 7 < LJ) {
            float4 u0 = *(const float4*)(b2 + c8);
            float4 u1 = *(const float4*)(b2 + c8 + 4);
            sum = ((u0.x + u0.y) + (u0.z + u0.w)) + ((u1.x + u1.y) + (u1.z + u1.w));
        }
        bband[tid] = sum;
    }
    // stage w2f chunk kb=0 (rows 0..31), coalesced float4
    #pragma unroll
    for (int s = 0; s < 4; ++s) {
        int slot = tid + 512 * s;                      // 2048 float4 slots
        int row = slot >> 6, c4 = slot & 63;
        long col = C0 + 4 * c4;
        float4 v = (col < LJ) ? *(const float4*)(W2 + (long)row * LJ + col) : z4;
        *(float4*)(&w2f[row * 256 + 4 * c4]) = v;
    }
    __syncthreads();

    int lane = tid & 63, wv = tid >> 6;
    int q = lane >> 4, r = lane & 15;
    f32x4 acc[2][4];
    #pragma unroll
    for (int c = 0; c < 2; ++c)
        #pragma unroll
        for (int b = 0; b < 4; ++b) acc[c][b] = (f32x4){0.f, 0.f, 0.f, 0.f};

    // wbandT rows for i = 0..31 from LDS
    #pragma unroll
    for (int s = 0; s < 2; ++s) {
        int en = tid + 512 * s;                        // 1024 entries
        int i = en >> 5, tl = en & 31;
        const float* p = &w2f[i * 256 + 8 * tl];
        wbandT[tl * 68 + i] = ((p[0] + p[1]) + (p[2] + p[3])) + ((p[4] + p[5]) + (p[6] + p[7]));
    }
    // MFMA kb=0, B frags from LDS
    #pragma unroll
    for (int ctl = 0; ctl < 2; ++ctl) {
        int ct = wv * 2 + ctl;
        unsigned short hh[8];
        #pragma unroll
        for (int e = 0; e < 8; ++e)
            hh[e] = f2bu(w2f[(8 * q + e) * 256 + 16 * ct + r]);
        uint4 braw = pack8(hh);
        #pragma unroll
        for (int bt = 0; bt < 4; ++bt) {
            uint4 araw = *(const uint4*)(&afr[((bt * 2 + 0) * 64 + lane) * 8]);
            acc[ctl][bt] = mfma16(araw, braw, acc[ctl][bt]);
        }
    }
    __syncthreads();                                   // done reading w2f(kb0)
    // stage w2f chunk kb=1 (rows 32..63)
    #pragma unroll
    for (int s = 0; s < 4; ++s) {
        int slot = tid + 512 * s;
        int row = slot >> 6, c4 = slot & 63;
        long col = C0 + 4 * c4;
        float4 v = (col < LJ) ? *(const float4*)(W2 + (long)(32 + row) * LJ + col) : z4;
        *(float4*)(&w2f[row * 256 + 4 * c4]) = v;
    }
    __syncthreads();
    // wbandT rows for i = 32..63
    #pragma unroll
    for (int s = 0; s < 2; ++s) {
        int en = tid + 512 * s;
        int i2 = en >> 5, tl = en & 31;
        const float* p = &w2f[i2 * 256 + 8 * tl];
        wbandT[tl * 68 + 32 + i2] = ((p[0] + p[1]) + (p[2] + p[3])) + ((p[4] + p[5]) + (p[6] + p[7]));
    }
    // MFMA kb=1
    #pragma unroll
    for (int ctl = 0; ctl < 2; ++ctl) {
        int ct = wv * 2 + ctl;
        unsigned short hh[8];
        #pragma unroll
        for (int e = 0; e < 8; ++e)
            hh[e] = f2bu(w2f[(8 * q + e) * 256 + 16 * ct + r]);
        uint4 braw = pack8(hh);
        #pragma unroll
        for (int bt = 0; bt < 4; ++bt) {
            uint4 araw = *(const uint4*)(&afr[((bt * 2 + 1) * 64 + lane) * 8]);
            acc[ctl][bt] = mfma16(araw, braw, acc[ctl][bt]);
        }
    }
    __syncthreads();                                   // wbandT complete

    // exact-f32 edc1d, vectorized: thread owns column tl (const), batches b0+16s
    {
        int tl = tid & 31;
        int b0 = tid >> 5;                             // 0..15
        long c8 = C0 + 8 * tl;
        if (c8 + 7 < LJ) {
            float d0 = bband[tl], d1 = d0, d2 = d0, d3 = d0;
            #pragma unroll
            for (int i0 = 0; i0 < 64; i0 += 8) {
                float4 wA = *(const float4*)(&wbandT[tl * 68 + i0]);
                float4 wB = *(const float4*)(&wbandT[tl * 68 + i0 + 4]);
                {
                    float4 hA = *(const float4*)(&h1T[(b0 +  0) * 68 + i0]);
                    float4 hB = *(const float4*)(&h1T[(b0 +  0) * 68 + i0 + 4]);
                    d0 += hA.x*wA.x + hA.y*wA.y + hA.z*wA.z + hA.w*wA.w
                        + hB.x*wB.x + hB.y*wB.y + hB.z*wB.z + hB.w*wB.w;
                }
                {
                    float4 hA = *(const float4*)(&h1T[(b0 + 16) * 68 + i0]);
                    float4 hB = *(const float4*)(&h1T[(b0 + 16) * 68 + i0 + 4]);
                    d1 += hA.x*wA.x + hA.y*wA.y + hA.z*wA.z + hA.w*wA.w
                        + hB.x*wB.x + hB.y*wB.y + hB.z*wB.z + hB.w*wB.w;
                }
                {
                    float4 hA = *(const float4*)(&h1T[(b0 + 32) * 68 + i0]);
                    float4 hB = *(const float4*)(&h1T[(b0 + 32) * 68 + i0 + 4]);
                    d2 += hA.x*wA.x + hA.y*wA.y + hA.z*wA.z + hA.w*wA.w
                        + hB.x*wB.x + hB.y*wB.y + hB.z*wB.z + hB.w*wB.w;
                }
                {
                    float4 hA = *(const float4*)(&h1T[(b0 + 48) * 68 + i0]);
                    float4 hB = *(const float4*)(&h1T[(b0 + 48) * 68 + i0 + 4]);
                    d3 += hA.x*wA.x + hA.y*wA.y + hA.z*wA.z + hA.w*wA.w
                        + hB.x*wB.x + hB.y*wB.y + hB.z*wB.z + hB.w*wB.w;
                }
            }
            int tcol = (int)(C0 >> 3) + tl;
            edc1d[(long)(b0 +  0) * TN + tcol] = d0 * 0.125f;
            edc1d[(long)(b0 + 16) * TN + tcol] = d1 * 0.125f;
            edc1d[(long)(b0 + 32) * TN + tcol] = d2 * 0.125f;
            edc1d[(long)(b0 + 48) * TN + tcol] = d3 * 0.125f;
        }
    }

    // epilogue: edc stores + band partial sums
    float psum[4][4];
    #pragma unroll
    for (int bt = 0; bt < 4; ++bt)
        #pragma unroll
        for (int rg = 0; rg < 4; ++rg) psum[bt][rg] = 0.f;
    #pragma unroll
    for (int ctl = 0; ctl < 2; ++ctl) {
        int ct = wv * 2 + ctl;
        long col = C0 + 16 * ct + r;
        bool okc = col < LJ;
        float bias = okc ? b2[col] : 0.f;
        #pragma unroll
        for (int bt = 0; bt < 4; ++bt) {
            #pragma unroll
            for (int rg = 0; rg < 4; ++rg) {
                float v = acc[ctl][bt][rg] + bias;      // 0 for invalid cols (B staged 0)
                if (okc) edc[(long)(16 * bt + 4 * q + rg) * LJ + col] = v;
                float sps = v + __shfl_xor(v, 8);       // band-sum over {r, r^8}
                psum[bt][rg] += sps;
            }
        }
    }
    if (r < 8) {
        #pragma unroll
        for (int bt = 0; bt < 4; ++bt)
            #pragma unroll
            for (int rg = 0; rg < 4; ++rg)
                P[(long)blockIdx.x * 512 + (16 * bt + 4 * q + rg) * 8 + r] = psum[bt][rg];
    }
}

// ---------------- sum block partials -> sums[b][band][{all,q1,q4}] ----------------
__global__ __launch_bounds__(512) void k_redsum(const float* __restrict__ P,
                                                float* __restrict__ sums)
{
    int g = blockIdx.x, t = threadIdx.x;           // t = batch*8 + band
    int b = t >> 3, band = t & 7;
    int s0 = g * 16, s1 = s0 + 16;
    if (s1 > 1001) s1 = 1001;
    float all = 0.f, q1 = 0.f, q4 = 0.f;
    for (int blk = s0; blk < s1; ++blk) {
        float v = P[(long)blk * 512 + t];
        all += v;
        if (blk < 250) q1 += v;                    // t < 8000  <=> j < 64000
        if (blk >= 750) q4 += v;                   // t >= 24000 <=> j >= 192000
    }
    atomicAdd(&sums[b * 24 + band * 3 + 0], all);
    atomicAdd(&sums[b * 24 + band * 3 + 1], q1);
    atomicAdd(&sums[b * 24 + band * 3 + 2], q4);
}

// ---------------- small MLP head: one block per batch row, f32 outputs ----------------
__global__ __launch_bounds__(64) void k_mlp(const float* __restrict__ x,
    const float* __restrict__ sums,
    const float* __restrict__ eW1, const float* __restrict__ eb1,
    const float* __restrict__ eW2, const float* __restrict__ eb2,
    const float* __restrict__ dW1, const float* __restrict__ db1,
    const float* __restrict__ dW2, const float* __restrict__ db2,
    const float* __restrict__ aW1, const float* __restrict__ ab1,
    const float* __restrict__ aW2, const float* __restrict__ ab2,
    const float* __restrict__ bW1, const float* __restrict__ bb1,
    const float* __restrict__ bW2, const float* __restrict__ bb2,
    float* __restrict__ out_lk, float* __restrict__ out_a, float* __restrict__ out_b)
{
    int b = blockIdx.x, o = threadIdx.x;
    __shared__ float feat[16], a1[64], hh[64], t1[64];
    if (o < 16) {
        float v;
        if (o < 8) v = sums[b * 24 + o * 3] * (1.f / 32001.f);
        else {
            int band = o - 8;
            v = sums[b * 24 + band * 3 + 2] * (1.f / 8001.f)
              - sums[b * 24 + band * 3 + 1] * (1.f / 8000.f);
        }
        feat[o] = v;
    }
    __syncthreads();
    {   float acc = eb1[o];
        #pragma unroll
        for (int c = 0; c < 16; ++c) acc += feat[c] * eW1[c * 64 + o];
        a1[o] = fmaxf(acc, 0.f); }
    __syncthreads();
    {   float acc = eb2[o];
        for (int c = 0; c < 64; ++c) acc += a1[c] * eW2[c * 64 + o];
        hh[o] = fmaxf(acc, 0.f); }
    __syncthreads();
    {   float acc = db1[o];
        #pragma unroll
        for (int c = 0; c < 3; ++c) acc += x[b * 16 + c] * dW1[c * 64 + o];
        for (int c = 0; c < 64; ++c) acc += hh[c] * dW1[(3 + c) * 64 + o];
        t1[o] = fmaxf(acc, 0.f); }
    __syncthreads();
    if (o < 16) {
        float acc = db2[o];
        for (int c = 0; c < 64; ++c) acc += t1[c] * dW2[c * 16 + o];
        out_lk[b * 16 + o] = acc;
    }
    __syncthreads();
    if (o < 32) {
        float acc = ab1[o];
        for (int c = 0; c < 64; ++c) acc += hh[c] * aW1[c * 32 + o];
        t1[o] = fmaxf(acc, 0.f);
    }
    __syncthreads();
    if (o < 16) {
        float acc = ab2[o];
        for (int c = 0; c < 32; ++c) acc += t1[c] * aW2[c * 16 + o];
        out_a[b * 16 + o] = acc;
    }
    __syncthreads();
    if (o < 32) {
        float acc = bb1[o];
        for (int c = 0; c < 64; ++c) acc += hh[c] * bW1[c * 32 + o];
        t1[o] = fmaxf(acc, 0.f);
    }
    __syncthreads();
    if (o < 16) {
        float acc = bb2[o];
        for (int c = 0; c < 32; ++c) acc += t1[c] * bW2[c * 16 + o];
        out_b[b * 16 + o] = acc;
    }
}

// ---------------- parity stage 1: packed bits (per-(b, 256-chunk) inclusive XOR scan) ----------
__global__ __launch_bounds__(256) void k_par1(const int* __restrict__ flips,
                                              unsigned* __restrict__ parbits,
                                              unsigned* __restrict__ ctot)
{
    int b = blockIdx.x, c = blockIdx.y, tid = threadIdx.x;
    int t = c * 256 + tid;
    int bit = (t == 0) ? 0 : (flips[(long)b * OUT_LEN + t] & 1);
    int lane = tid & 63, wv = tid >> 6;
    unsigned long long mask = __ballot(bit != 0);
    int below = ((int)__popcll(mask & ((1ull << lane) - 1ull))) & 1;
    int incl = below ^ bit;
    __shared__ int wtot[4];
    if (lane == 0) wtot[wv] = ((int)__popcll(mask)) & 1;
    __syncthreads();
    int pre = 0;
    for (int w = 0; w < wv; ++w) pre ^= wtot[w];
    int inclB = pre ^ incl;
    unsigned long long m2 = __ballot(inclB != 0);
    if (lane == 0)  parbits[b * 1000 + c * 8 + wv * 2 + 0] = (unsigned)(m2 & 0xffffffffull);
    if (lane == 32) parbits[b * 1000 + c * 8 + wv * 2 + 1] = (unsigned)(m2 >> 32);
    if (tid == 0) ctot[c * 64 + b] = (unsigned)(wtot[0] ^ wtot[1] ^ wtot[2] ^ wtot[3]);
}

// ---------------- parity stage 2: exclusive prefix over chunks ----------------
__global__ __launch_bounds__(64) void k_par2(const unsigned* __restrict__ ctot,
                                             unsigned* __restrict__ cpref)
{
    int b = threadIdx.x;
    unsigned carry = 0;
    for (int c = 0; c < 125; ++c) {
        cpref[c * 64 + b] = carry;
        carry ^= ctot[c * 64 + b];
    }
}

// ------- MFMA Toeplitz conv (late+early) + amp + sign -> rir ----------------------------------
__global__ __launch_bounds__(512) void k_convm(const float* __restrict__ edc1d,
    const float* __restrict__ lk, const float* __restrict__ eg,
    const unsigned* __restrict__ parbits, const unsigned* __restrict__ cpref,
    float* __restrict__ rir)
{
    __shared__ float kerf[1024];
    __shared__ __align__(16) unsigned short afr[33 * 64 * 8];  // A frags [kb][lane][e]
    __shared__ __align__(16) unsigned short sbf[3136];         // swizzled bf16 window
    __shared__ float sf32[2049];
    int b = blockIdx.x, tb0 = blockIdx.y * 2048, tid = threadIdx.x;
    const float* src = edc1d + (long)b * TN;
    for (int k = tid; k < 1024; k += 512)
        kerf[k] = lk[k] + (k < 43 ? eg[k] : 0.f);
    for (int ch = tid; ch < 388; ch += 512) {
        unsigned short h[8];
        #pragma unroll
        for (int e = 0; e < 8; ++e) {
            int gt = tb0 + ch * 8 + e - 1031;
            float v = (gt >= 0 && gt <= OUT_LEN) ? src[gt] : 0.f;
            h[e] = f2bu(v);
        }
        int cs = ch ^ ((ch >> 3) & 7);
        *(uint4*)(&sbf[cs * 8]) = pack8(h);
    }
    for (int u = tid; u < 2049; u += 512) {
        int gt = tb0 + u;
        sf32[u] = (gt <= OUT_LEN) ? src[gt] : 0.f;
    }
    __syncthreads();
    for (int sl = tid; sl < 33 * 64; sl += 512) {
        int kb = sl >> 6, l = sl & 63;
        int x0 = kb * 32 - 1 + (l & 15) - 8 * (l >> 4);    // x = x0 - e
        unsigned short h[8];
        #pragma unroll
        for (int e = 0; e < 8; ++e) {
            int x = x0 - e;
            float v = (x >= 0 && x < 1024) ? kerf[x] : 0.f;
            h[e] = f2bu(v);
        }
        *(uint4*)(&afr[sl * 8]) = pack8(h);
    }
    __syncthreads();
    int lane = tid & 63, wv = tid >> 6;                    // 8 waves, 1 C-tile each
    int tb = tb0 + wv * 256;
    int cq = wv * 256 + 16 * (lane & 15) + 8 * (lane >> 4) + 1032;  // B chunk base (kb=0)
    f32x4 acc = {0.f, 0.f, 0.f, 0.f};
    for (int kb = 0; kb < 33; ++kb) {
        uint4 araw = *(const uint4*)(&afr[(kb * 64 + lane) * 8]);
        int ch = (cq - (kb << 5)) >> 3;
        int cs = ch ^ ((ch >> 3) & 7);
        uint4 braw = *(const uint4*)(&sbf[cs * 8]);
        acc = mfma16(araw, braw, acc);
    }
    int c = lane & 15, q = lane >> 4;
    int t4 = tb + 16 * c + 4 * q;
    if (t4 < OUT_LEN) {
        int u0 = t4 - tb0;
        unsigned pw = parbits[b * 1000 + (t4 >> 5)];       // 4 bits same word (t4%4==0)
        unsigned cp = cpref[(t4 >> 8) * 64 + b] & 1u;
        int sh = t4 & 31;
        float sv[5];
        #pragma unroll
        for (int e = 0; e < 5; ++e) sv[e] = sf32[u0 + e];
        float r[4];
        #pragma unroll
        for (int reg = 0; reg < 4; ++reg) {
            float diff = sv[reg] - sv[reg + 1];
            float amp = diff > 0.f ? sqrtf(diff) : 0.f;
            unsigned p = ((pw >> (sh + reg)) & 1u) ^ cp;
            r[reg] = acc[reg] * amp * (p ? -1.f : 1.f);
        }
        *(float4*)(rir + (long)b * OUT_LEN + t4) = make_float4(r[0], r[1], r[2], r[3]);
    }
}

extern "C" void kernel_launch(void* const* d_in, const int* in_sizes, int n_in,
                              void* d_out, int out_size, void* d_ws, size_t ws_size,
                              hipStream_t stream) {
    (void)in_sizes; (void)n_in; (void)out_size; (void)ws_size;
    const float* x    = (const float*)d_in[0];
    const float* lW1  = (const float*)d_in[1];  const float* lb1 = (const float*)d_in[2];
    const float* lW2  = (const float*)d_in[3];  const float* lb2 = (const float*)d_in[4];
    const float* eW1  = (const float*)d_in[5];  const float* eb1 = (const float*)d_in[6];
    const float* eW2  = (const float*)d_in[7];  const float* eb2 = (const float*)d_in[8];
    const float* dW1  = (const float*)d_in[9];  const float* db1 = (const float*)d_in[10];
    const float* dW2  = (const float*)d_in[11]; const float* db2 = (const float*)d_in[12];
    const float* aW1  = (const float*)d_in[13]; const float* ab1 = (const float*)d_in[14];
    const float* aW2  = (const float*)d_in[15]; const float* ab2 = (const float*)d_in[16];
    const float* bW1  = (const float*)d_in[17]; const float* bb1 = (const float*)d_in[18];
    const float* bW2  = (const float*)d_in[19]; const float* bb2 = (const float*)d_in[20];
    const float* eg   = (const float*)d_in[21]; const float* lkk = (const float*)d_in[22];
    const int* flips  = (const int*)d_in[23];

    float* out = (float*)d_out;                    // f32 output buffer
    float* rir = out;                              // 2,048,000
    float* edc = out + 2048000;                    // 16,384,512
    float* olk = out + 18432512;                   // 1,024
    float* oa  = out + 18433536;                   // 1,024
    float* ob  = out + 18434560;                   // 1,024

    // -------- ws layout --------
    char* wsb = (char*)d_ws;
    float*    ws_h1   = (float*)(wsb + 1024);       // 16,384 B
    unsigned* ws_ct   = (unsigned*)(wsb + 18432);   // 32,000 B
    unsigned* ws_cp   = (unsigned*)(wsb + 50688);   // 32,000 B
    unsigned* ws_pb   = (unsigned*)(wsb + 82944);   // 256,000 B
    float*    ws_sums = (float*)(wsb + 339200);     // 6,144 B
    float*    ws_e1d  = (float*)(wsb + 346112);     // 8,192,256 B -> ends 8,538,368
    float*    ws_part = (float*)(wsb + 8538368);    // 1001*512*4 = 2,050,048 B

    hipMemsetAsync(ws_sums, 0, 64 * 24 * sizeof(float), stream);

    k_h1<<<16, 256, 0, stream>>>(x, lW1, lb1, ws_h1);
    k_par1<<<dim3(64, 125), 256, 0, stream>>>(flips, ws_pb, ws_ct);
    k_par2<<<1, 64, 0, stream>>>(ws_ct, ws_cp);
    k_gemm<<<1001, 512, 0, stream>>>(lW2, lb2, ws_h1, edc, ws_e1d, ws_part);
    k_redsum<<<63, 512, 0, stream>>>(ws_part, ws_sums);
    k_mlp<<<64, 64, 0, stream>>>(x, ws_sums, eW1, eb1, eW2, eb2, dW1, db1, dW2, db2,
                                 aW1, ab1, aW2, ab2, bW1, bb1, bW2, bb2, olk, oa, ob);
    k_convm<<<dim3(64, 16), 512, 0, stream>>>(ws_e1d, lkk, eg, ws_pb, ws_cp, rir);
}